// Round 16
// baseline (595.994 us; speedup 1.0000x reference)
//
#include <hip/hip_runtime.h>
#include <cstddef>
#include <cstdint>

#define N_SRC 100000
#define N_DST 100000
#define NE    1000000
#define D     128
#define R     3
#define NEG   0.2f
#define N3    (R * N_DST)                 // 300000 flattened (r,dst) rows
#define NE3   (R * NE)                    // 3000000 edges
#define NE3_4 (NE3 / 4)                   // 750000 int4 packets
#define NB3   ((N3 + 255) / 256)          // 1172
#define NROWS_SEM (R * N_DST)
#define NBH64 ((N_SRC + 63) / 64)         // 1563 blocks per relation (64-row tiles)
#define NBS   ((NROWS_SEM + 127) / 128)   // 2344
#define NGRP  8                           // dst-range groups (≈ XCDs)
#define GBLK  256                         // blocks per group
#define GRNG  (N3 / NGRP)                 // 37500 rows per group
#define NZB   293                         // zero-blocks for rowptr3
#define M1_C  (NGRP * GBLK)               // 2048 count blocks
#define M1_E  (N_DST / 4)                 // 25000 er blocks

typedef __attribute__((ext_vector_type(8))) short bf16x8;
typedef __attribute__((ext_vector_type(4))) float f32x4;

__device__ __forceinline__ float b2f(unsigned short u) {
    union { unsigned int i; float f; } v; v.i = ((unsigned int)u) << 16; return v.f;
}
__device__ __forceinline__ unsigned short f2b(float f) {
    union { float f; unsigned int i; } v; v.f = f;
    unsigned int x = v.i;
    return (unsigned short)((x + 0x7fffu + ((x >> 16) & 1u)) >> 16);  // RNE
}
__device__ __forceinline__ float ubits(unsigned u) {
    union { unsigned i; float f; } v; v.i = u; return v.f;
}
__device__ __forceinline__ unsigned cvt_pk_bf16(float a, float b) {
    unsigned r;
    asm("v_cvt_pk_bf16_f32 %0, %1, %2" : "=v"(r) : "v"(a), "v"(b));
    return r;
}
__device__ __forceinline__ float eluf(float x) {
    return x > 0.f ? x : expm1f(x);
}

// Merged prologue: blocks 0..2 = {W transpose->bf16, v[r]}, block 3 = W1t,
// blocks 4.. = zero rowptr3
__global__ void prep_all(const float* __restrict__ fcW, const float* __restrict__ attn_r,
                         const float* __restrict__ sem_W1,
                         unsigned short* __restrict__ Wh, unsigned short* __restrict__ W1t,
                         float* __restrict__ v, int* __restrict__ rowptr3) {
    int b = blockIdx.x;
    int tid = threadIdx.x;
    if (b < R) {
        for (int i = tid; i < D * D; i += 256) {
            int n = i >> 7, k = i & 127;
            Wh[(size_t)b * D * D + i] = f2b(fcW[(size_t)b * D * D + k * D + n]);
        }
        if (tid < D) {
            const float* Wrow = fcW + ((size_t)b * D + tid) * D;
            const float* ar = attn_r + b * D;
            float s = 0.f;
            #pragma unroll 4
            for (int j = 0; j < D; j++) s += Wrow[j] * ar[j];
            v[b * D + tid] = s;
        }
    } else if (b == R) {
        for (int i = tid; i < D * D; i += 256) {
            int n = i >> 7, k = i & 127;
            W1t[i] = f2b(sem_W1[k * D + n]);
        }
    } else {
        int i = (b - R - 1) * 1024 + tid * 4;
        if (i + 4 <= N3 + 1) *(int4*)(rowptr3 + i) = make_int4(0, 0, 0, 0);
        else for (int j = i; j < N3 + 1; j++) rowptr3[j] = 0;
    }
}

// ---------- MEGA1: count (int4 edge scan, 4x MLP) || er_all (BW-bound) ----------
// Round-15 diagnosis: count was latency-bound (VALUBusy 11%, 460 GB/s, MLP=1).
// int4 loads put 4 edges behind each load latency. NE % 4 == 0 -> each int4
// packet is within one relation (uniform r).
__global__ __launch_bounds__(256) void count_er(const int* __restrict__ ed3,
                                                int* __restrict__ cnt3,
                                                const float* __restrict__ dst_feat,
                                                const float* __restrict__ v,
                                                float* __restrict__ er3) {
    int bid = blockIdx.x;
    if (bid < M1_C) {
        int g = bid & (NGRP - 1);
        int j = bid >> 3;
        int lo = g * GRNG, hi = lo + GRNG;
        const int4* ed4 = (const int4*)ed3;
        for (int idx = j * 256 + threadIdx.x; idx < NE3_4; idx += GBLK * 256) {
            int4 e = ed4[idx];
            int base = idx << 2;
            int roff = ((base >= NE) + (base >= 2 * NE)) * N_DST;
            int i0 = roff + e.x, i1 = roff + e.y, i2 = roff + e.z, i3 = roff + e.w;
            if (i0 >= lo && i0 < hi) atomicAdd(&cnt3[i0], 1);
            if (i1 >= lo && i1 < hi) atomicAdd(&cnt3[i1], 1);
            if (i2 >= lo && i2 < hi) atomicAdd(&cnt3[i2], 1);
            if (i3 >= lo && i3 < hi) atomicAdd(&cnt3[i3], 1);
        }
    } else {
        int bid2 = bid - M1_C;
        int gw = (bid2 * 256 + threadIdx.x) >> 6;
        int lane = threadIdx.x & 63;
        if (gw >= N_DST) return;
        float2 x = ((const float2*)(dst_feat + (size_t)gw * D))[lane];
        #pragma unroll
        for (int r = 0; r < R; r++) {
            float2 vv = ((const float2*)(v + r * D))[lane];
            float s = x.x * vv.x + x.y * vv.y;
            #pragma unroll
            for (int off = 32; off; off >>= 1) s += __shfl_xor(s, off);
            if (lane == 0) er3[(size_t)r * N_DST + gw] = s;
        }
    }
}

__global__ void scan_blocks(int* __restrict__ rowptr, int* __restrict__ bsum) {
    __shared__ int tmp[256];
    int i = blockIdx.x * 256 + threadIdx.x;
    int x = (i < N3) ? rowptr[i] : 0;
    tmp[threadIdx.x] = x;
    __syncthreads();
    #pragma unroll
    for (int off = 1; off < 256; off <<= 1) {
        int v = (threadIdx.x >= off) ? tmp[threadIdx.x - off] : 0;
        __syncthreads();
        tmp[threadIdx.x] += v;
        __syncthreads();
    }
    if (i < N3) rowptr[i] = tmp[threadIdx.x] - x;
    if (threadIdx.x == 255) bsum[blockIdx.x] = tmp[255];
}

// each block sums bsum[0..bid) itself (L2-resident) — replaces serial scan_bsum
__global__ __launch_bounds__(256) void add_offsets2(int* __restrict__ rowptr,
                                                    const int* __restrict__ bsum,
                                                    int* __restrict__ cursor) {
    __shared__ int rr[4];
    int bid = blockIdx.x, tid = threadIdx.x;
    int s = 0;
    for (int j = tid; j < bid; j += 256) s += bsum[j];
    #pragma unroll
    for (int off = 32; off; off >>= 1) s += __shfl_xor(s, off);
    if ((tid & 63) == 0) rr[tid >> 6] = s;
    __syncthreads();
    int base = rr[0] + rr[1] + rr[2] + rr[3];
    int i = bid * 256 + tid;
    if (i < N3) {
        int vv = rowptr[i] + base;
        rowptr[i] = vv;
        cursor[i] = vv;
    }
    if (i == 0) rowptr[N3] = NE3;
}

// ---------- place: XCD-range-filtered, int4 edge scan (4x MLP) ----------
__global__ __launch_bounds__(256) void place_f(const int* __restrict__ es3,
                                               const int* __restrict__ ed3,
                                               int* __restrict__ cursor3,
                                               int* __restrict__ csr_src) {
    int g = blockIdx.x & (NGRP - 1);
    int j = blockIdx.x / NGRP;
    int lo = g * GRNG, hi = lo + GRNG;
    const int4* ed4 = (const int4*)ed3;
    const int4* es4 = (const int4*)es3;
    for (int idx = j * 256 + threadIdx.x; idx < NE3_4; idx += GBLK * 256) {
        int4 e = ed4[idx];
        int4 s = es4[idx];
        int base = idx << 2;
        int roff = ((base >= NE) + (base >= 2 * NE)) * N_DST;
        int i0 = roff + e.x, i1 = roff + e.y, i2 = roff + e.z, i3 = roff + e.w;
        if (i0 >= lo && i0 < hi) { int p = atomicAdd(&cursor3[i0], 1); csr_src[p] = s.x; }
        if (i1 >= lo && i1 < hi) { int p = atomicAdd(&cursor3[i1], 1); csr_src[p] = s.y; }
        if (i2 >= lo && i2 < hi) { int p = atomicAdd(&cursor3[i2], 1); csr_src[p] = s.z; }
        if (i3 >= lo && i3 < hi) { int p = atomicAdd(&cursor3[i3], 1); csr_src[p] = s.w; }
    }
}

// ---------- MFMA GEMM: H = X @ W (bf16x2), fused el (standalone) ----------
__global__ __launch_bounds__(256) void gemm_h_all(const float* __restrict__ src_feat,
        const unsigned short* __restrict__ Wh, const float* __restrict__ attn_l,
        unsigned short* __restrict__ H3, float* __restrict__ el3) {
    __shared__ short Xh[64 * 128], Xl[64 * 128];   // 16 KB each
    __shared__ short Bh[128 * 128];                // 32 KB
    int tid = threadIdx.x;
    int rb = blockIdx.x / NBH64, bb = blockIdx.x % NBH64;
    const float* X = src_feat + (size_t)rb * N_SRC * D;
    const unsigned short* WhR = Wh + (size_t)rb * D * D;
    const float* al = attn_l + rb * D;
    unsigned short* H = H3 + (size_t)rb * N_SRC * D;
    float* el = el3 + (size_t)rb * N_SRC;
    size_t row0 = (size_t)bb * 64;
    #pragma unroll
    for (int p = 0; p < 8; p++) {
        int c = p * 256 + tid;
        int m = c >> 5, c4 = c & 31;
        float4 xv = make_float4(0.f, 0.f, 0.f, 0.f);
        if (row0 + m < N_SRC) xv = ((const float4*)(X + (row0 + m) * D))[c4];
        unsigned h01 = cvt_pk_bf16(xv.x, xv.y);
        unsigned h23 = cvt_pk_bf16(xv.z, xv.w);
        float hx = ubits(h01 << 16), hy = ubits(h01 & 0xffff0000u);
        float hz = ubits(h23 << 16), hw = ubits(h23 & 0xffff0000u);
        unsigned l01 = cvt_pk_bf16(xv.x - hx, xv.y - hy);
        unsigned l23 = cvt_pk_bf16(xv.z - hz, xv.w - hw);
        int idx = m * 128 + (((c4 >> 1) ^ (m & 7)) << 3) + ((c4 & 1) << 2);
        *(uint2*)&Xh[idx] = make_uint2(h01, h23);
        *(uint2*)&Xl[idx] = make_uint2(l01, l23);
    }
    #pragma unroll
    for (int p = 0; p < 8; p++) {
        int c = p * 256 + tid;
        int n = c >> 4, cb = c & 15;
        int idx = n * 128 + ((cb ^ (n & 7)) << 3);
        *(uint4*)&Bh[idx] = ((const uint4*)WhR)[c];
    }
    __syncthreads();

    int w = tid >> 6, lane = tid & 63, lr = lane & 15, lg = lane >> 4;
    f32x4 acc[8];
    #pragma unroll
    for (int nt = 0; nt < 8; nt++) acc[nt] = (f32x4){0.f, 0.f, 0.f, 0.f};
    int m = w * 16 + lr;
    #pragma unroll
    for (int kk = 0; kk < 4; kk++) {
        int cb = kk * 4 + lg;
        int ia = m * 128 + ((cb ^ (m & 7)) << 3);
        bf16x8 ah = *(const bf16x8*)&Xh[ia];
        bf16x8 alo = *(const bf16x8*)&Xl[ia];
        #pragma unroll
        for (int nt = 0; nt < 8; nt++) {
            int n = nt * 16 + lr;
            int ib = n * 128 + ((cb ^ (n & 7)) << 3);
            bf16x8 bh = *(const bf16x8*)&Bh[ib];
            acc[nt] = __builtin_amdgcn_mfma_f32_16x16x32_bf16(ah, bh, acc[nt], 0, 0, 0);
            acc[nt] = __builtin_amdgcn_mfma_f32_16x16x32_bf16(alo, bh, acc[nt], 0, 0, 0);
        }
    }
    float alv[8];
    #pragma unroll
    for (int nt = 0; nt < 8; nt++) alv[nt] = al[nt * 16 + lr];
    #pragma unroll
    for (int reg = 0; reg < 4; reg++) {
        float ep = 0.f;
        #pragma unroll
        for (int nt = 0; nt < 8; nt++) ep = fmaf(acc[nt][reg], alv[nt], ep);
        ep += __shfl_xor(ep, 1); ep += __shfl_xor(ep, 2);
        ep += __shfl_xor(ep, 4); ep += __shfl_xor(ep, 8);
        size_t row = row0 + w * 16 + lg * 4 + reg;
        if (lr == 0 && row < N_SRC) el[row] = ep;
    }
    short* Ht = Xh;
    #pragma unroll
    for (int reg = 0; reg < 4; reg++) {
        int rowl = w * 16 + lg * 4 + reg;
        #pragma unroll
        for (int nt = 0; nt < 8; nt++)
            Ht[rowl * 128 + nt * 16 + lr] = (short)f2b(acc[nt][reg]);
    }
    __syncthreads();
    #pragma unroll
    for (int p = 0; p < 4; p++) {
        int c = p * 256 + tid;
        int mm = c >> 4, q = c & 15;
        size_t row = row0 + mm;
        if (row < N_SRC)
            ((uint4*)(H + row * D))[q] = *(const uint4*)&Ht[mm * 128 + q * 8];
    }
}

// ---------- MFMA GEMM: semantic partials (z is bf16) ----------
__global__ __launch_bounds__(512) void gemm_sem(const unsigned short* __restrict__ Z,
        const unsigned short* __restrict__ W1t, const float* __restrict__ b1,
        const float* __restrict__ w2, float* __restrict__ psem) {
    __shared__ short Xh[16384], Bh[16384];
    __shared__ float redw[8][4];
    int tid = threadIdx.x;
    size_t row0 = (size_t)blockIdx.x * 128;
    #pragma unroll
    for (int p = 0; p < 4; p++) {
        int c = p * 512 + tid;
        int m = c >> 4, cb = c & 15;
        uint4 xv = make_uint4(0u, 0u, 0u, 0u);
        if (row0 + m < NROWS_SEM) xv = ((const uint4*)(Z + (row0 + m) * D))[cb];
        int idx = m * 128 + ((cb ^ (m & 7)) << 3);
        *(uint4*)&Xh[idx] = xv;
    }
    #pragma unroll
    for (int p = 0; p < 4; p++) {
        int c = p * 512 + tid;
        int n = c >> 4, cb = c & 15;
        int idx = n * 128 + ((cb ^ (n & 7)) << 3);
        *(uint4*)&Bh[idx] = ((const uint4*)W1t)[c];
    }
    __syncthreads();

    int w = tid >> 6, lane = tid & 63, lr = lane & 15, lg = lane >> 4;
    f32x4 acc[8];
    #pragma unroll
    for (int nt = 0; nt < 8; nt++) acc[nt] = (f32x4){0.f, 0.f, 0.f, 0.f};
    int m = w * 16 + lr;
    #pragma unroll
    for (int kk = 0; kk < 4; kk++) {
        int cb = kk * 4 + lg;
        int ia = m * 128 + ((cb ^ (m & 7)) << 3);
        bf16x8 ah = *(const bf16x8*)&Xh[ia];
        #pragma unroll
        for (int nt = 0; nt < 8; nt++) {
            int n = nt * 16 + lr;
            int ib = n * 128 + ((cb ^ (n & 7)) << 3);
            bf16x8 bh = *(const bf16x8*)&Bh[ib];
            acc[nt] = __builtin_amdgcn_mfma_f32_16x16x32_bf16(ah, bh, acc[nt], 0, 0, 0);
        }
    }
    float b1v[8], w2v[8];
    #pragma unroll
    for (int nt = 0; nt < 8; nt++) { b1v[nt] = b1[nt * 16 + lr]; w2v[nt] = w2[nt * 16 + lr]; }
    float rs0 = 0.f, rs1 = 0.f, rs2 = 0.f;
    #pragma unroll
    for (int reg = 0; reg < 4; reg++) {
        size_t row = row0 + w * 16 + lg * 4 + reg;
        float sv = 0.f;
        #pragma unroll
        for (int nt = 0; nt < 8; nt++)
            sv += tanhf(acc[nt][reg] + b1v[nt]) * w2v[nt];
        sv += __shfl_xor(sv, 1); sv += __shfl_xor(sv, 2);
        sv += __shfl_xor(sv, 4); sv += __shfl_xor(sv, 8);
        if (lr == 0 && row < NROWS_SEM) {
            int r = (int)(row / N_DST);
            if (r == 0) rs0 += sv; else if (r == 1) rs1 += sv; else rs2 += sv;
        }
    }
    rs0 += __shfl_xor(rs0, 16); rs0 += __shfl_xor(rs0, 32);
    rs1 += __shfl_xor(rs1, 16); rs1 += __shfl_xor(rs1, 32);
    rs2 += __shfl_xor(rs2, 16); rs2 += __shfl_xor(rs2, 32);
    if (lane == 0) { redw[w][0] = rs0; redw[w][1] = rs1; redw[w][2] = rs2; }
    __syncthreads();
    if (tid < 3) {
        float s = 0.f;
        #pragma unroll
        for (int i = 0; i < 8; i++) s += redw[i][tid];
        psem[blockIdx.x * 3 + tid] = s;
    }
}

// ---------- per-(r,dst) gather + softmax + elu (round-13 verified) ----------
__global__ __launch_bounds__(256) void aggregate_all(const unsigned short* __restrict__ hsrc3,
                                                     const int* __restrict__ csr_src,
                                                     const int* __restrict__ rowptr3,
                                                     const float* __restrict__ el3,
                                                     const float* __restrict__ er3,
                                                     const float* __restrict__ gat_bias,
                                                     unsigned short* __restrict__ z3) {
    int gw3 = __builtin_amdgcn_readfirstlane((int)((blockIdx.x * blockDim.x + threadIdx.x) >> 6));
    int lane = threadIdx.x & 63;
    if (gw3 >= N3) return;
    int r = gw3 / N_DST;
    int beg = __builtin_amdgcn_readfirstlane(rowptr3[gw3]);
    int end = __builtin_amdgcn_readfirstlane(rowptr3[gw3 + 1]);
    float erd = er3[gw3];
    const char* hsb = (const char*)(hsrc3 + (size_t)r * N_SRC * D);
    const char* elb = (const char*)(el3 + (size_t)r * N_SRC);
    unsigned loff = ((unsigned)lane) << 2;
    float2 acc = make_float2(0.f, 0.f);
    float sum = 0.f;
    int i = beg;
    for (; i + 8 <= end; i += 8) {
        int s[8];
        #pragma unroll
        for (int k = 0; k < 8; k++)
            s[k] = __builtin_amdgcn_readfirstlane(csr_src[i + k]);
        float x[8];
        #pragma unroll
        for (int k = 0; k < 8; k++) {
            float e = *(const float*)(elb + ((unsigned)s[k] << 2)) + erd;
            e = fmaxf(e, NEG * e);
            x[k] = __expf(e);
        }
        ushort2 u[8];
        #pragma unroll
        for (int k = 0; k < 8; k++)
            u[k] = *(const ushort2*)(hsb + (((unsigned)s[k] << 8) + loff));
        #pragma unroll
        for (int k = 0; k < 8; k++) {
            acc.x = fmaf(x[k], b2f(u[k].x), acc.x);
            acc.y = fmaf(x[k], b2f(u[k].y), acc.y);
            sum += x[k];
        }
    }
    for (; i + 4 <= end; i += 4) {
        int s0 = __builtin_amdgcn_readfirstlane(csr_src[i]);
        int s1 = __builtin_amdgcn_readfirstlane(csr_src[i + 1]);
        int s2 = __builtin_amdgcn_readfirstlane(csr_src[i + 2]);
        int s3 = __builtin_amdgcn_readfirstlane(csr_src[i + 3]);
        float e0 = *(const float*)(elb + ((unsigned)s0 << 2)) + erd;
        float e1 = *(const float*)(elb + ((unsigned)s1 << 2)) + erd;
        float e2 = *(const float*)(elb + ((unsigned)s2 << 2)) + erd;
        float e3 = *(const float*)(elb + ((unsigned)s3 << 2)) + erd;
        e0 = fmaxf(e0, NEG * e0); e1 = fmaxf(e1, NEG * e1);
        e2 = fmaxf(e2, NEG * e2); e3 = fmaxf(e3, NEG * e3);
        float x0 = __expf(e0), x1 = __expf(e1);
        float x2 = __expf(e2), x3 = __expf(e3);
        ushort2 u0 = *(const ushort2*)(hsb + (((unsigned)s0 << 8) + loff));
        ushort2 u1 = *(const ushort2*)(hsb + (((unsigned)s1 << 8) + loff));
        ushort2 u2 = *(const ushort2*)(hsb + (((unsigned)s2 << 8) + loff));
        ushort2 u3 = *(const ushort2*)(hsb + (((unsigned)s3 << 8) + loff));
        acc.x = fmaf(x0, b2f(u0.x), acc.x);
        acc.y = fmaf(x0, b2f(u0.y), acc.y);
        acc.x = fmaf(x1, b2f(u1.x), acc.x);
        acc.y = fmaf(x1, b2f(u1.y), acc.y);
        acc.x = fmaf(x2, b2f(u2.x), acc.x);
        acc.y = fmaf(x2, b2f(u2.y), acc.y);
        acc.x = fmaf(x3, b2f(u3.x), acc.x);
        acc.y = fmaf(x3, b2f(u3.y), acc.y);
        sum += (x0 + x1) + (x2 + x3);
    }
    for (; i < end; i++) {
        int s0 = __builtin_amdgcn_readfirstlane(csr_src[i]);
        float e0 = *(const float*)(elb + ((unsigned)s0 << 2)) + erd;
        e0 = fmaxf(e0, NEG * e0);
        float x0 = __expf(e0);
        ushort2 u0 = *(const ushort2*)(hsb + (((unsigned)s0 << 8) + loff));
        acc.x = fmaf(x0, b2f(u0.x), acc.x);
        acc.y = fmaf(x0, b2f(u0.y), acc.y);
        sum += x0;
    }
    float inv = sum > 0.f ? 1.f / sum : 0.f;
    float2 b = ((const float2*)(gat_bias + r * D))[lane];
    ushort2 zu;
    zu.x = f2b(eluf(fmaf(acc.x, inv, b.x)));
    zu.y = f2b(eluf(fmaf(acc.y, inv, b.y)));
    ((ushort2*)(z3 + (size_t)gw3 * D))[lane] = zu;
}

__global__ void finalize_a(const float* __restrict__ psem, float* __restrict__ a_ws,
                           float* __restrict__ out_tail) {
    __shared__ float red[4][4];
    float s0 = 0.f, s1 = 0.f, s2 = 0.f;
    for (int b = threadIdx.x; b < NBS; b += 256) {
        s0 += psem[b * 3]; s1 += psem[b * 3 + 1]; s2 += psem[b * 3 + 2];
    }
    #pragma unroll
    for (int off = 32; off; off >>= 1) {
        s0 += __shfl_xor(s0, off); s1 += __shfl_xor(s1, off); s2 += __shfl_xor(s2, off);
    }
    int w = threadIdx.x >> 6;
    if ((threadIdx.x & 63) == 0) { red[w][0] = s0; red[w][1] = s1; red[w][2] = s2; }
    __syncthreads();
    if (threadIdx.x == 0) {
        float w0 = 0.f, w1 = 0.f, w2v = 0.f;
        #pragma unroll
        for (int i = 0; i < 4; i++) { w0 += red[i][0]; w1 += red[i][1]; w2v += red[i][2]; }
        w0 /= (float)N_DST; w1 /= (float)N_DST; w2v /= (float)N_DST;
        float m = fmaxf(w0, fmaxf(w1, w2v));
        float e0 = expf(w0 - m), e1 = expf(w1 - m), e2 = expf(w2v - m);
        float s = e0 + e1 + e2;
        a_ws[0] = e0 / s; a_ws[1] = e1 / s; a_ws[2] = e2 / s;
        out_tail[0] = e0 / s; out_tail[1] = e1 / s; out_tail[2] = e2 / s;
    }
}

// z_out = sum_r a[r] * z[r]  (z bf16, out fp32), 8 elems/thread
__global__ __launch_bounds__(256) void combine(const unsigned short* __restrict__ z3,
                                               const float* __restrict__ a,
                                               float* __restrict__ out) {
    size_t f = (size_t)blockIdx.x * blockDim.x + threadIdx.x;  // uint4 (8 bf16) index
    if (f >= (size_t)N_DST * D / 8) return;
    float accv[8] = {};
    #pragma unroll
    for (int r = 0; r < R; r++) {
        float ar = a[r];
        uint4 u = ((const uint4*)z3)[(size_t)r * (N_DST * D / 8) + f];
        unsigned int uu[4] = {u.x, u.y, u.z, u.w};
        #pragma unroll
        for (int q = 0; q < 4; q++) {
            accv[2 * q]     = fmaf(ar, b2f((unsigned short)(uu[q] & 0xffff)), accv[2 * q]);
            accv[2 * q + 1] = fmaf(ar, b2f((unsigned short)(uu[q] >> 16)), accv[2 * q + 1]);
        }
    }
    float4* o4 = (float4*)(out + f * 8);
    o4[0] = make_float4(accv[0], accv[1], accv[2], accv[3]);
    o4[1] = make_float4(accv[4], accv[5], accv[6], accv[7]);
}

extern "C" void kernel_launch(void* const* d_in, const int* in_sizes, int n_in,
                              void* d_out, int out_size, void* d_ws, size_t ws_size,
                              hipStream_t stream) {
    const float* dst_feat = (const float*)d_in[0];
    const float* src_feat = (const float*)d_in[1];
    const float* fcW      = (const float*)d_in[2];
    const float* attn_l   = (const float*)d_in[3];
    const float* attn_r   = (const float*)d_in[4];
    const float* gat_bias = (const float*)d_in[5];
    const float* sem_W1   = (const float*)d_in[6];
    const float* sem_b1   = (const float*)d_in[7];
    const float* sem_w2   = (const float*)d_in[8];
    const int* edge_src   = (const int*)d_in[9];
    const int* edge_dst   = (const int*)d_in[10];
    float* out = (float*)d_out;

    char* p = (char*)d_ws;
    auto alloc = [&](size_t bytes) {
        p = (char*)(((uintptr_t)p + 255) & ~(uintptr_t)255);
        char* r = p; p += bytes; return (void*)r;
    };
    unsigned short* z3   = (unsigned short*)alloc((size_t)N3 * D * sizeof(short));
    unsigned short* hsrc3= (unsigned short*)alloc((size_t)R * N_SRC * D * sizeof(short));
    float* el3    = (float*)alloc((size_t)R * N_SRC * sizeof(float));
    float* er3    = (float*)alloc((size_t)R * N_DST * sizeof(float));
    float* v      = (float*)alloc(R * D * sizeof(float));
    float* a      = (float*)alloc(R * sizeof(float));
    float* psem   = (float*)alloc((size_t)NBS * 3 * sizeof(float));
    unsigned short* Whi  = (unsigned short*)alloc((size_t)R * D * D * sizeof(short));
    unsigned short* W1t  = (unsigned short*)alloc((size_t)D * D * sizeof(short));
    int* rowptr3 = (int*)alloc((size_t)(N3 + 1) * sizeof(int));
    int* cursor3 = (int*)alloc((size_t)N3 * sizeof(int));
    int* bsum    = (int*)alloc(2048 * sizeof(int));
    int* csr_src = (int*)alloc((size_t)NE3 * sizeof(int));

    // 1. prologue: W prep + v + W1t + rowptr3 zero
    prep_all<<<R + 1 + NZB, 256, 0, stream>>>(fcW, attn_r, sem_W1, Whi, W1t, v, rowptr3);
    // 2. count (int4 atomics) || er (BW) — LDS-free fusion
    count_er<<<M1_C + M1_E, 256, 0, stream>>>(edge_dst, rowptr3, dst_feat, v, er3);
    // 3-4. scan
    scan_blocks<<<NB3, 256, 0, stream>>>(rowptr3, bsum);
    add_offsets2<<<NB3, 256, 0, stream>>>(rowptr3, bsum, cursor3);
    // 5. place (int4, standalone, full occupancy)
    place_f<<<NGRP * GBLK, 256, 0, stream>>>(edge_src, edge_dst, cursor3, csr_src);
    // 6. gemm_h (standalone, 2 blocks/CU)
    gemm_h_all<<<R * NBH64, 256, 0, stream>>>(src_feat, Whi, attn_l, hsrc3, el3);
    // 7. gather + softmax + elu -> z (bf16)
    aggregate_all<<<N3 / 4, 256, 0, stream>>>(hsrc3, csr_src, rowptr3, el3, er3,
                                              gat_bias, z3);
    // 8-10. semantic attention + combine
    gemm_sem<<<NBS, 512, 0, stream>>>(z3, W1t, sem_b1, sem_w2, psem);
    finalize_a<<<1, 256, 0, stream>>>(psem, a, out + (size_t)N_DST * D);
    combine<<<(N_DST * D / 8 + 255) / 256, 256, 0, stream>>>(z3, a, out);
}

// Round 17
// 591.924 us; speedup vs baseline: 1.0069x; 1.0069x over previous
//
#include <hip/hip_runtime.h>
#include <cstddef>
#include <cstdint>

#define N_SRC 100000
#define N_DST 100000
#define NE    1000000
#define D     128
#define R     3
#define NEG   0.2f
#define N3    (R * N_DST)                 // 300000 flattened (r,dst) rows
#define NE3   (R * NE)                    // 3000000 edges
#define NE3_4 (NE3 / 4)                   // 750000 int4 packets
#define NB3   ((N3 + 255) / 256)          // 1172
#define NROWS_SEM (R * N_DST)
#define NBH64 ((N_SRC + 63) / 64)         // 1563 blocks per relation (64-row tiles)
#define NBS   ((NROWS_SEM + 127) / 128)   // 2344
#define NGRP  8                           // dst-range groups (place only)
#define GBLK  256                         // blocks per group
#define GRNG  (N3 / NGRP)                 // 37500 rows per group
#define NZB   293                         // zero-blocks for rowptr3
#define M1_C  ((NE3_4 + 255) / 256)       // 2930 count blocks (1 int4/thread)
#define M1_E  (N_DST / 4)                 // 25000 er blocks

typedef __attribute__((ext_vector_type(8))) short bf16x8;
typedef __attribute__((ext_vector_type(4))) float f32x4;

__device__ __forceinline__ float b2f(unsigned short u) {
    union { unsigned int i; float f; } v; v.i = ((unsigned int)u) << 16; return v.f;
}
__device__ __forceinline__ unsigned short f2b(float f) {
    union { float f; unsigned int i; } v; v.f = f;
    unsigned int x = v.i;
    return (unsigned short)((x + 0x7fffu + ((x >> 16) & 1u)) >> 16);  // RNE
}
__device__ __forceinline__ float ubits(unsigned u) {
    union { unsigned i; float f; } v; v.i = u; return v.f;
}
__device__ __forceinline__ unsigned cvt_pk_bf16(float a, float b) {
    unsigned r;
    asm("v_cvt_pk_bf16_f32 %0, %1, %2" : "=v"(r) : "v"(a), "v"(b));
    return r;
}
__device__ __forceinline__ float eluf(float x) {
    return x > 0.f ? x : expm1f(x);
}

// Merged prologue: blocks 0..2 = {W transpose->bf16, v[r]}, block 3 = W1t,
// blocks 4.. = zero rowptr3
__global__ void prep_all(const float* __restrict__ fcW, const float* __restrict__ attn_r,
                         const float* __restrict__ sem_W1,
                         unsigned short* __restrict__ Wh, unsigned short* __restrict__ W1t,
                         float* __restrict__ v, int* __restrict__ rowptr3) {
    int b = blockIdx.x;
    int tid = threadIdx.x;
    if (b < R) {
        for (int i = tid; i < D * D; i += 256) {
            int n = i >> 7, k = i & 127;
            Wh[(size_t)b * D * D + i] = f2b(fcW[(size_t)b * D * D + k * D + n]);
        }
        if (tid < D) {
            const float* Wrow = fcW + ((size_t)b * D + tid) * D;
            const float* ar = attn_r + b * D;
            float s = 0.f;
            #pragma unroll 4
            for (int j = 0; j < D; j++) s += Wrow[j] * ar[j];
            v[b * D + tid] = s;
        }
    } else if (b == R) {
        for (int i = tid; i < D * D; i += 256) {
            int n = i >> 7, k = i & 127;
            W1t[i] = f2b(sem_W1[k * D + n]);
        }
    } else {
        int i = (b - R - 1) * 1024 + tid * 4;
        if (i + 4 <= N3 + 1) *(int4*)(rowptr3 + i) = make_int4(0, 0, 0, 0);
        else for (int j = i; j < N3 + 1; j++) rowptr3[j] = 0;
    }
}

// ---------- MEGA1: UNFILTERED count (1 int4/thread, probe for atomic floor)
// || er_all (BW-bound). Round-16 null: filtered count with 4x MLP was
// duration-identical -> suspect 3M device-scope atomics are the floor
// (atomics resolve at device coherence point; XCD filter can't help them).
// This variant reads each edge ONCE with zero loop overhead: if it also
// lands ~155us the atomic floor is confirmed (count+place structural).
__global__ __launch_bounds__(256) void count_er(const int* __restrict__ ed3,
                                                int* __restrict__ cnt3,
                                                const float* __restrict__ dst_feat,
                                                const float* __restrict__ v,
                                                float* __restrict__ er3) {
    int bid = blockIdx.x;
    if (bid < M1_C) {
        int idx = bid * 256 + threadIdx.x;
        if (idx >= NE3_4) return;
        int4 e = ((const int4*)ed3)[idx];
        int base = idx << 2;
        int roff = ((base >= NE) + (base >= 2 * NE)) * N_DST;
        atomicAdd(&cnt3[roff + e.x], 1);
        atomicAdd(&cnt3[roff + e.y], 1);
        atomicAdd(&cnt3[roff + e.z], 1);
        atomicAdd(&cnt3[roff + e.w], 1);
    } else {
        int bid2 = bid - M1_C;
        int gw = (bid2 * 256 + threadIdx.x) >> 6;
        int lane = threadIdx.x & 63;
        if (gw >= N_DST) return;
        float2 x = ((const float2*)(dst_feat + (size_t)gw * D))[lane];
        #pragma unroll
        for (int r = 0; r < R; r++) {
            float2 vv = ((const float2*)(v + r * D))[lane];
            float s = x.x * vv.x + x.y * vv.y;
            #pragma unroll
            for (int off = 32; off; off >>= 1) s += __shfl_xor(s, off);
            if (lane == 0) er3[(size_t)r * N_DST + gw] = s;
        }
    }
}

__global__ void scan_blocks(int* __restrict__ rowptr, int* __restrict__ bsum) {
    __shared__ int tmp[256];
    int i = blockIdx.x * 256 + threadIdx.x;
    int x = (i < N3) ? rowptr[i] : 0;
    tmp[threadIdx.x] = x;
    __syncthreads();
    #pragma unroll
    for (int off = 1; off < 256; off <<= 1) {
        int v = (threadIdx.x >= off) ? tmp[threadIdx.x - off] : 0;
        __syncthreads();
        tmp[threadIdx.x] += v;
        __syncthreads();
    }
    if (i < N3) rowptr[i] = tmp[threadIdx.x] - x;
    if (threadIdx.x == 255) bsum[blockIdx.x] = tmp[255];
}

// each block sums bsum[0..bid) itself (L2-resident) — replaces serial scan_bsum
__global__ __launch_bounds__(256) void add_offsets2(int* __restrict__ rowptr,
                                                    const int* __restrict__ bsum,
                                                    int* __restrict__ cursor) {
    __shared__ int rr[4];
    int bid = blockIdx.x, tid = threadIdx.x;
    int s = 0;
    for (int j = tid; j < bid; j += 256) s += bsum[j];
    #pragma unroll
    for (int off = 32; off; off >>= 1) s += __shfl_xor(s, off);
    if ((tid & 63) == 0) rr[tid >> 6] = s;
    __syncthreads();
    int base = rr[0] + rr[1] + rr[2] + rr[3];
    int i = bid * 256 + tid;
    if (i < N3) {
        int vv = rowptr[i] + base;
        rowptr[i] = vv;
        cursor[i] = vv;
    }
    if (i == 0) rowptr[N3] = NE3;
}

// ---------- place: XCD-range-filtered, int4 edge scan ----------
// (filter kept: csr_src PLAIN STORES need the L2-resident window to fill
// 64B lines — round-4's unfiltered place had 17x write amplification)
__global__ __launch_bounds__(256) void place_f(const int* __restrict__ es3,
                                               const int* __restrict__ ed3,
                                               int* __restrict__ cursor3,
                                               int* __restrict__ csr_src) {
    int g = blockIdx.x & (NGRP - 1);
    int j = blockIdx.x / NGRP;
    int lo = g * GRNG, hi = lo + GRNG;
    const int4* ed4 = (const int4*)ed3;
    const int4* es4 = (const int4*)es3;
    for (int idx = j * 256 + threadIdx.x; idx < NE3_4; idx += GBLK * 256) {
        int4 e = ed4[idx];
        int4 s = es4[idx];
        int base = idx << 2;
        int roff = ((base >= NE) + (base >= 2 * NE)) * N_DST;
        int i0 = roff + e.x, i1 = roff + e.y, i2 = roff + e.z, i3 = roff + e.w;
        if (i0 >= lo && i0 < hi) { int p = atomicAdd(&cursor3[i0], 1); csr_src[p] = s.x; }
        if (i1 >= lo && i1 < hi) { int p = atomicAdd(&cursor3[i1], 1); csr_src[p] = s.y; }
        if (i2 >= lo && i2 < hi) { int p = atomicAdd(&cursor3[i2], 1); csr_src[p] = s.z; }
        if (i3 >= lo && i3 < hi) { int p = atomicAdd(&cursor3[i3], 1); csr_src[p] = s.w; }
    }
}

// ---------- MFMA GEMM: H = X @ W (bf16x2), fused el (standalone) ----------
__global__ __launch_bounds__(256) void gemm_h_all(const float* __restrict__ src_feat,
        const unsigned short* __restrict__ Wh, const float* __restrict__ attn_l,
        unsigned short* __restrict__ H3, float* __restrict__ el3) {
    __shared__ short Xh[64 * 128], Xl[64 * 128];   // 16 KB each
    __shared__ short Bh[128 * 128];                // 32 KB
    int tid = threadIdx.x;
    int rb = blockIdx.x / NBH64, bb = blockIdx.x % NBH64;
    const float* X = src_feat + (size_t)rb * N_SRC * D;
    const unsigned short* WhR = Wh + (size_t)rb * D * D;
    const float* al = attn_l + rb * D;
    unsigned short* H = H3 + (size_t)rb * N_SRC * D;
    float* el = el3 + (size_t)rb * N_SRC;
    size_t row0 = (size_t)bb * 64;
    #pragma unroll
    for (int p = 0; p < 8; p++) {
        int c = p * 256 + tid;
        int m = c >> 5, c4 = c & 31;
        float4 xv = make_float4(0.f, 0.f, 0.f, 0.f);
        if (row0 + m < N_SRC) xv = ((const float4*)(X + (row0 + m) * D))[c4];
        unsigned h01 = cvt_pk_bf16(xv.x, xv.y);
        unsigned h23 = cvt_pk_bf16(xv.z, xv.w);
        float hx = ubits(h01 << 16), hy = ubits(h01 & 0xffff0000u);
        float hz = ubits(h23 << 16), hw = ubits(h23 & 0xffff0000u);
        unsigned l01 = cvt_pk_bf16(xv.x - hx, xv.y - hy);
        unsigned l23 = cvt_pk_bf16(xv.z - hz, xv.w - hw);
        int idx = m * 128 + (((c4 >> 1) ^ (m & 7)) << 3) + ((c4 & 1) << 2);
        *(uint2*)&Xh[idx] = make_uint2(h01, h23);
        *(uint2*)&Xl[idx] = make_uint2(l01, l23);
    }
    #pragma unroll
    for (int p = 0; p < 8; p++) {
        int c = p * 256 + tid;
        int n = c >> 4, cb = c & 15;
        int idx = n * 128 + ((cb ^ (n & 7)) << 3);
        *(uint4*)&Bh[idx] = ((const uint4*)WhR)[c];
    }
    __syncthreads();

    int w = tid >> 6, lane = tid & 63, lr = lane & 15, lg = lane >> 4;
    f32x4 acc[8];
    #pragma unroll
    for (int nt = 0; nt < 8; nt++) acc[nt] = (f32x4){0.f, 0.f, 0.f, 0.f};
    int m = w * 16 + lr;
    #pragma unroll
    for (int kk = 0; kk < 4; kk++) {
        int cb = kk * 4 + lg;
        int ia = m * 128 + ((cb ^ (m & 7)) << 3);
        bf16x8 ah = *(const bf16x8*)&Xh[ia];
        bf16x8 alo = *(const bf16x8*)&Xl[ia];
        #pragma unroll
        for (int nt = 0; nt < 8; nt++) {
            int n = nt * 16 + lr;
            int ib = n * 128 + ((cb ^ (n & 7)) << 3);
            bf16x8 bh = *(const bf16x8*)&Bh[ib];
            acc[nt] = __builtin_amdgcn_mfma_f32_16x16x32_bf16(ah, bh, acc[nt], 0, 0, 0);
            acc[nt] = __builtin_amdgcn_mfma_f32_16x16x32_bf16(alo, bh, acc[nt], 0, 0, 0);
        }
    }
    float alv[8];
    #pragma unroll
    for (int nt = 0; nt < 8; nt++) alv[nt] = al[nt * 16 + lr];
    #pragma unroll
    for (int reg = 0; reg < 4; reg++) {
        float ep = 0.f;
        #pragma unroll
        for (int nt = 0; nt < 8; nt++) ep = fmaf(acc[nt][reg], alv[nt], ep);
        ep += __shfl_xor(ep, 1); ep += __shfl_xor(ep, 2);
        ep += __shfl_xor(ep, 4); ep += __shfl_xor(ep, 8);
        size_t row = row0 + w * 16 + lg * 4 + reg;
        if (lr == 0 && row < N_SRC) el[row] = ep;
    }
    short* Ht = Xh;
    #pragma unroll
    for (int reg = 0; reg < 4; reg++) {
        int rowl = w * 16 + lg * 4 + reg;
        #pragma unroll
        for (int nt = 0; nt < 8; nt++)
            Ht[rowl * 128 + nt * 16 + lr] = (short)f2b(acc[nt][reg]);
    }
    __syncthreads();
    #pragma unroll
    for (int p = 0; p < 4; p++) {
        int c = p * 256 + tid;
        int mm = c >> 4, q = c & 15;
        size_t row = row0 + mm;
        if (row < N_SRC)
            ((uint4*)(H + row * D))[q] = *(const uint4*)&Ht[mm * 128 + q * 8];
    }
}

// ---------- MFMA GEMM: semantic partials (z is bf16) ----------
__global__ __launch_bounds__(512) void gemm_sem(const unsigned short* __restrict__ Z,
        const unsigned short* __restrict__ W1t, const float* __restrict__ b1,
        const float* __restrict__ w2, float* __restrict__ psem) {
    __shared__ short Xh[16384], Bh[16384];
    __shared__ float redw[8][4];
    int tid = threadIdx.x;
    size_t row0 = (size_t)blockIdx.x * 128;
    #pragma unroll
    for (int p = 0; p < 4; p++) {
        int c = p * 512 + tid;
        int m = c >> 4, cb = c & 15;
        uint4 xv = make_uint4(0u, 0u, 0u, 0u);
        if (row0 + m < NROWS_SEM) xv = ((const uint4*)(Z + (row0 + m) * D))[cb];
        int idx = m * 128 + ((cb ^ (m & 7)) << 3);
        *(uint4*)&Xh[idx] = xv;
    }
    #pragma unroll
    for (int p = 0; p < 4; p++) {
        int c = p * 512 + tid;
        int n = c >> 4, cb = c & 15;
        int idx = n * 128 + ((cb ^ (n & 7)) << 3);
        *(uint4*)&Bh[idx] = ((const uint4*)W1t)[c];
    }
    __syncthreads();

    int w = tid >> 6, lane = tid & 63, lr = lane & 15, lg = lane >> 4;
    f32x4 acc[8];
    #pragma unroll
    for (int nt = 0; nt < 8; nt++) acc[nt] = (f32x4){0.f, 0.f, 0.f, 0.f};
    int m = w * 16 + lr;
    #pragma unroll
    for (int kk = 0; kk < 4; kk++) {
        int cb = kk * 4 + lg;
        int ia = m * 128 + ((cb ^ (m & 7)) << 3);
        bf16x8 ah = *(const bf16x8*)&Xh[ia];
        #pragma unroll
        for (int nt = 0; nt < 8; nt++) {
            int n = nt * 16 + lr;
            int ib = n * 128 + ((cb ^ (n & 7)) << 3);
            bf16x8 bh = *(const bf16x8*)&Bh[ib];
            acc[nt] = __builtin_amdgcn_mfma_f32_16x16x32_bf16(ah, bh, acc[nt], 0, 0, 0);
        }
    }
    float b1v[8], w2v[8];
    #pragma unroll
    for (int nt = 0; nt < 8; nt++) { b1v[nt] = b1[nt * 16 + lr]; w2v[nt] = w2[nt * 16 + lr]; }
    float rs0 = 0.f, rs1 = 0.f, rs2 = 0.f;
    #pragma unroll
    for (int reg = 0; reg < 4; reg++) {
        size_t row = row0 + w * 16 + lg * 4 + reg;
        float sv = 0.f;
        #pragma unroll
        for (int nt = 0; nt < 8; nt++)
            sv += tanhf(acc[nt][reg] + b1v[nt]) * w2v[nt];
        sv += __shfl_xor(sv, 1); sv += __shfl_xor(sv, 2);
        sv += __shfl_xor(sv, 4); sv += __shfl_xor(sv, 8);
        if (lr == 0 && row < NROWS_SEM) {
            int r = (int)(row / N_DST);
            if (r == 0) rs0 += sv; else if (r == 1) rs1 += sv; else rs2 += sv;
        }
    }
    rs0 += __shfl_xor(rs0, 16); rs0 += __shfl_xor(rs0, 32);
    rs1 += __shfl_xor(rs1, 16); rs1 += __shfl_xor(rs1, 32);
    rs2 += __shfl_xor(rs2, 16); rs2 += __shfl_xor(rs2, 32);
    if (lane == 0) { redw[w][0] = rs0; redw[w][1] = rs1; redw[w][2] = rs2; }
    __syncthreads();
    if (tid < 3) {
        float s = 0.f;
        #pragma unroll
        for (int i = 0; i < 8; i++) s += redw[i][tid];
        psem[blockIdx.x * 3 + tid] = s;
    }
}

// ---------- per-(r,dst) gather + softmax + elu (round-13 verified) ----------
__global__ __launch_bounds__(256) void aggregate_all(const unsigned short* __restrict__ hsrc3,
                                                     const int* __restrict__ csr_src,
                                                     const int* __restrict__ rowptr3,
                                                     const float* __restrict__ el3,
                                                     const float* __restrict__ er3,
                                                     const float* __restrict__ gat_bias,
                                                     unsigned short* __restrict__ z3) {
    int gw3 = __builtin_amdgcn_readfirstlane((int)((blockIdx.x * blockDim.x + threadIdx.x) >> 6));
    int lane = threadIdx.x & 63;
    if (gw3 >= N3) return;
    int r = gw3 / N_DST;
    int beg = __builtin_amdgcn_readfirstlane(rowptr3[gw3]);
    int end = __builtin_amdgcn_readfirstlane(rowptr3[gw3 + 1]);
    float erd = er3[gw3];
    const char* hsb = (const char*)(hsrc3 + (size_t)r * N_SRC * D);
    const char* elb = (const char*)(el3 + (size_t)r * N_SRC);
    unsigned loff = ((unsigned)lane) << 2;
    float2 acc = make_float2(0.f, 0.f);
    float sum = 0.f;
    int i = beg;
    for (; i + 8 <= end; i += 8) {
        int s[8];
        #pragma unroll
        for (int k = 0; k < 8; k++)
            s[k] = __builtin_amdgcn_readfirstlane(csr_src[i + k]);
        float x[8];
        #pragma unroll
        for (int k = 0; k < 8; k++) {
            float e = *(const float*)(elb + ((unsigned)s[k] << 2)) + erd;
            e = fmaxf(e, NEG * e);
            x[k] = __expf(e);
        }
        ushort2 u[8];
        #pragma unroll
        for (int k = 0; k < 8; k++)
            u[k] = *(const ushort2*)(hsb + (((unsigned)s[k] << 8) + loff));
        #pragma unroll
        for (int k = 0; k < 8; k++) {
            acc.x = fmaf(x[k], b2f(u[k].x), acc.x);
            acc.y = fmaf(x[k], b2f(u[k].y), acc.y);
            sum += x[k];
        }
    }
    for (; i + 4 <= end; i += 4) {
        int s0 = __builtin_amdgcn_readfirstlane(csr_src[i]);
        int s1 = __builtin_amdgcn_readfirstlane(csr_src[i + 1]);
        int s2 = __builtin_amdgcn_readfirstlane(csr_src[i + 2]);
        int s3 = __builtin_amdgcn_readfirstlane(csr_src[i + 3]);
        float e0 = *(const float*)(elb + ((unsigned)s0 << 2)) + erd;
        float e1 = *(const float*)(elb + ((unsigned)s1 << 2)) + erd;
        float e2 = *(const float*)(elb + ((unsigned)s2 << 2)) + erd;
        float e3 = *(const float*)(elb + ((unsigned)s3 << 2)) + erd;
        e0 = fmaxf(e0, NEG * e0); e1 = fmaxf(e1, NEG * e1);
        e2 = fmaxf(e2, NEG * e2); e3 = fmaxf(e3, NEG * e3);
        float x0 = __expf(e0), x1 = __expf(e1);
        float x2 = __expf(e2), x3 = __expf(e3);
        ushort2 u0 = *(const ushort2*)(hsb + (((unsigned)s0 << 8) + loff));
        ushort2 u1 = *(const ushort2*)(hsb + (((unsigned)s1 << 8) + loff));
        ushort2 u2 = *(const ushort2*)(hsb + (((unsigned)s2 << 8) + loff));
        ushort2 u3 = *(const ushort2*)(hsb + (((unsigned)s3 << 8) + loff));
        acc.x = fmaf(x0, b2f(u0.x), acc.x);
        acc.y = fmaf(x0, b2f(u0.y), acc.y);
        acc.x = fmaf(x1, b2f(u1.x), acc.x);
        acc.y = fmaf(x1, b2f(u1.y), acc.y);
        acc.x = fmaf(x2, b2f(u2.x), acc.x);
        acc.y = fmaf(x2, b2f(u2.y), acc.y);
        acc.x = fmaf(x3, b2f(u3.x), acc.x);
        acc.y = fmaf(x3, b2f(u3.y), acc.y);
        sum += (x0 + x1) + (x2 + x3);
    }
    for (; i < end; i++) {
        int s0 = __builtin_amdgcn_readfirstlane(csr_src[i]);
        float e0 = *(const float*)(elb + ((unsigned)s0 << 2)) + erd;
        e0 = fmaxf(e0, NEG * e0);
        float x0 = __expf(e0);
        ushort2 u0 = *(const ushort2*)(hsb + (((unsigned)s0 << 8) + loff));
        acc.x = fmaf(x0, b2f(u0.x), acc.x);
        acc.y = fmaf(x0, b2f(u0.y), acc.y);
        sum += x0;
    }
    float inv = sum > 0.f ? 1.f / sum : 0.f;
    float2 b = ((const float2*)(gat_bias + r * D))[lane];
    ushort2 zu;
    zu.x = f2b(eluf(fmaf(acc.x, inv, b.x)));
    zu.y = f2b(eluf(fmaf(acc.y, inv, b.y)));
    ((ushort2*)(z3 + (size_t)gw3 * D))[lane] = zu;
}

__global__ void finalize_a(const float* __restrict__ psem, float* __restrict__ a_ws,
                           float* __restrict__ out_tail) {
    __shared__ float red[4][4];
    float s0 = 0.f, s1 = 0.f, s2 = 0.f;
    for (int b = threadIdx.x; b < NBS; b += 256) {
        s0 += psem[b * 3]; s1 += psem[b * 3 + 1]; s2 += psem[b * 3 + 2];
    }
    #pragma unroll
    for (int off = 32; off; off >>= 1) {
        s0 += __shfl_xor(s0, off); s1 += __shfl_xor(s1, off); s2 += __shfl_xor(s2, off);
    }
    int w = threadIdx.x >> 6;
    if ((threadIdx.x & 63) == 0) { red[w][0] = s0; red[w][1] = s1; red[w][2] = s2; }
    __syncthreads();
    if (threadIdx.x == 0) {
        float w0 = 0.f, w1 = 0.f, w2v = 0.f;
        #pragma unroll
        for (int i = 0; i < 4; i++) { w0 += red[i][0]; w1 += red[i][1]; w2v += red[i][2]; }
        w0 /= (float)N_DST; w1 /= (float)N_DST; w2v /= (float)N_DST;
        float m = fmaxf(w0, fmaxf(w1, w2v));
        float e0 = expf(w0 - m), e1 = expf(w1 - m), e2 = expf(w2v - m);
        float s = e0 + e1 + e2;
        a_ws[0] = e0 / s; a_ws[1] = e1 / s; a_ws[2] = e2 / s;
        out_tail[0] = e0 / s; out_tail[1] = e1 / s; out_tail[2] = e2 / s;
    }
}

// z_out = sum_r a[r] * z[r]  (z bf16, out fp32), 8 elems/thread
__global__ __launch_bounds__(256) void combine(const unsigned short* __restrict__ z3,
                                               const float* __restrict__ a,
                                               float* __restrict__ out) {
    size_t f = (size_t)blockIdx.x * blockDim.x + threadIdx.x;  // uint4 (8 bf16) index
    if (f >= (size_t)N_DST * D / 8) return;
    float accv[8] = {};
    #pragma unroll
    for (int r = 0; r < R; r++) {
        float ar = a[r];
        uint4 u = ((const uint4*)z3)[(size_t)r * (N_DST * D / 8) + f];
        unsigned int uu[4] = {u.x, u.y, u.z, u.w};
        #pragma unroll
        for (int q = 0; q < 4; q++) {
            accv[2 * q]     = fmaf(ar, b2f((unsigned short)(uu[q] & 0xffff)), accv[2 * q]);
            accv[2 * q + 1] = fmaf(ar, b2f((unsigned short)(uu[q] >> 16)), accv[2 * q + 1]);
        }
    }
    float4* o4 = (float4*)(out + f * 8);
    o4[0] = make_float4(accv[0], accv[1], accv[2], accv[3]);
    o4[1] = make_float4(accv[4], accv[5], accv[6], accv[7]);
}

extern "C" void kernel_launch(void* const* d_in, const int* in_sizes, int n_in,
                              void* d_out, int out_size, void* d_ws, size_t ws_size,
                              hipStream_t stream) {
    const float* dst_feat = (const float*)d_in[0];
    const float* src_feat = (const float*)d_in[1];
    const float* fcW      = (const float*)d_in[2];
    const float* attn_l   = (const float*)d_in[3];
    const float* attn_r   = (const float*)d_in[4];
    const float* gat_bias = (const float*)d_in[5];
    const float* sem_W1   = (const float*)d_in[6];
    const float* sem_b1   = (const float*)d_in[7];
    const float* sem_w2   = (const float*)d_in[8];
    const int* edge_src   = (const int*)d_in[9];
    const int* edge_dst   = (const int*)d_in[10];
    float* out = (float*)d_out;

    char* p = (char*)d_ws;
    auto alloc = [&](size_t bytes) {
        p = (char*)(((uintptr_t)p + 255) & ~(uintptr_t)255);
        char* r = p; p += bytes; return (void*)r;
    };
    unsigned short* z3   = (unsigned short*)alloc((size_t)N3 * D * sizeof(short));
    unsigned short* hsrc3= (unsigned short*)alloc((size_t)R * N_SRC * D * sizeof(short));
    float* el3    = (float*)alloc((size_t)R * N_SRC * sizeof(float));
    float* er3    = (float*)alloc((size_t)R * N_DST * sizeof(float));
    float* v      = (float*)alloc(R * D * sizeof(float));
    float* a      = (float*)alloc(R * sizeof(float));
    float* psem   = (float*)alloc((size_t)NBS * 3 * sizeof(float));
    unsigned short* Whi  = (unsigned short*)alloc((size_t)R * D * D * sizeof(short));
    unsigned short* W1t  = (unsigned short*)alloc((size_t)D * D * sizeof(short));
    int* rowptr3 = (int*)alloc((size_t)(N3 + 1) * sizeof(int));
    int* cursor3 = (int*)alloc((size_t)N3 * sizeof(int));
    int* bsum    = (int*)alloc(2048 * sizeof(int));
    int* csr_src = (int*)alloc((size_t)NE3 * sizeof(int));

    // 1. prologue: W prep + v + W1t + rowptr3 zero
    prep_all<<<R + 1 + NZB, 256, 0, stream>>>(fcW, attn_r, sem_W1, Whi, W1t, v, rowptr3);
    // 2. count (unfiltered, 1 int4/thread) || er (BW) — LDS-free fusion
    count_er<<<M1_C + M1_E, 256, 0, stream>>>(edge_dst, rowptr3, dst_feat, v, er3);
    // 3-4. scan
    scan_blocks<<<NB3, 256, 0, stream>>>(rowptr3, bsum);
    add_offsets2<<<NB3, 256, 0, stream>>>(rowptr3, bsum, cursor3);
    // 5. place (int4, filtered, standalone)
    place_f<<<NGRP * GBLK, 256, 0, stream>>>(edge_src, edge_dst, cursor3, csr_src);
    // 6. gemm_h (standalone, 2 blocks/CU)
    gemm_h_all<<<R * NBH64, 256, 0, stream>>>(src_feat, Whi, attn_l, hsrc3, el3);
    // 7. gather + softmax + elu -> z (bf16)
    aggregate_all<<<N3 / 4, 256, 0, stream>>>(hsrc3, csr_src, rowptr3, el3, er3,
                                              gat_bias, z3);
    // 8-10. semantic attention + combine
    gemm_sem<<<NBS, 512, 0, stream>>>(z3, W1t, sem_b1, sem_w2, psem);
    finalize_a<<<1, 256, 0, stream>>>(psem, a, out + (size_t)N_DST * D);
    combine<<<(N_DST * D / 8 + 255) / 256, 256, 0, stream>>>(z3, a, out);
}

// Round 18
// 436.243 us; speedup vs baseline: 1.3662x; 1.3569x over previous
//
#include <hip/hip_runtime.h>
#include <cstddef>
#include <cstdint>

#define N_SRC 100000
#define N_DST 100000
#define NE    1000000
#define D     128
#define R     3
#define NEG   0.2f
#define N3    (R * N_DST)                 // 300000 flattened (r,dst) rows
#define NE3   (R * NE)                    // 3000000 edges
#define NE3_4 (NE3 / 4)                   // 750000 int4 packets
#define NB3   ((N3 + 255) / 256)          // 1172
#define NROWS_SEM (R * N_DST)
#define NBH64 ((N_SRC + 63) / 64)         // 1563 blocks per relation
#define NBS   ((NROWS_SEM + 127) / 128)   // 2344
#define NGC   8                           // bin-range groups (XCD affinity)
#define BPG   32                          // blocks per group
#define BINS  37500                       // bins per group (146.5 KB LDS)
#define CBLK  (NGC * BPG)                 // 256 count/place blocks
#define PKTB  ((NE3_4 + BPG - 1) / BPG)   // 23438 int4 packets per block slice

typedef __attribute__((ext_vector_type(8))) short bf16x8;
typedef __attribute__((ext_vector_type(4))) float f32x4;

__device__ __forceinline__ float b2f(unsigned short u) {
    union { unsigned int i; float f; } v; v.i = ((unsigned int)u) << 16; return v.f;
}
__device__ __forceinline__ unsigned short f2b(float f) {
    union { float f; unsigned int i; } v; v.f = f;
    unsigned int x = v.i;
    return (unsigned short)((x + 0x7fffu + ((x >> 16) & 1u)) >> 16);  // RNE
}
__device__ __forceinline__ float ubits(unsigned u) {
    union { unsigned i; float f; } v; v.i = u; return v.f;
}
__device__ __forceinline__ unsigned cvt_pk_bf16(float a, float b) {
    unsigned r;
    asm("v_cvt_pk_bf16_f32 %0, %1, %2" : "=v"(r) : "v"(a), "v"(b));
    return r;
}
__device__ __forceinline__ float eluf(float x) {
    return x > 0.f ? x : expm1f(x);
}

// Prologue: blocks 0..2 = {W transpose->bf16, v[r]}, block 3 = W1t.
// (cnt3 no longer needs zeroing: reduce_pfx fully writes it.)
__global__ void prep_all(const float* __restrict__ fcW, const float* __restrict__ attn_r,
                         const float* __restrict__ sem_W1,
                         unsigned short* __restrict__ Wh, unsigned short* __restrict__ W1t,
                         float* __restrict__ v) {
    int b = blockIdx.x;
    int tid = threadIdx.x;
    if (b < R) {
        for (int i = tid; i < D * D; i += 256) {
            int n = i >> 7, k = i & 127;
            Wh[(size_t)b * D * D + i] = f2b(fcW[(size_t)b * D * D + k * D + n]);
        }
        if (tid < D) {
            const float* Wrow = fcW + ((size_t)b * D + tid) * D;
            const float* ar = attn_r + b * D;
            float s = 0.f;
            #pragma unroll 4
            for (int j = 0; j < D; j++) s += Wrow[j] * ar[j];
            v[b * D + tid] = s;
        }
    } else {
        for (int i = tid; i < D * D; i += 256) {
            int n = i >> 7, k = i & 127;
            W1t[i] = f2b(sem_W1[k * D + n]);
        }
    }
}

// er3[r][n] = dst_feat[n] . v[r]
__global__ __launch_bounds__(256) void er_all(const float* __restrict__ dst_feat,
                                              const float* __restrict__ v,
                                              float* __restrict__ er3) {
    int gw = (blockIdx.x * blockDim.x + threadIdx.x) >> 6;
    int lane = threadIdx.x & 63;
    if (gw >= N_DST) return;
    float2 x = ((const float2*)(dst_feat + (size_t)gw * D))[lane];
    #pragma unroll
    for (int r = 0; r < R; r++) {
        float2 vv = ((const float2*)(v + r * D))[lane];
        float s = x.x * vv.x + x.y * vv.y;
        #pragma unroll
        for (int off = 32; off; off >>= 1) s += __shfl_xor(s, off);
        if (lane == 0) er3[(size_t)r * N_DST + gw] = s;
    }
}

// ---------- count via LDS-privatized histograms (ZERO device atomics) ----------
// Round-17 probe confirmed 3M device atomics are a ~158us floor. Group g
// (= bid&7, XCD round-robin) owns bins [g*BINS,(g+1)*BINS); block b (=bid>>3)
// scans edge-slice b into a private 146.5 KB LDS histogram, then dumps it to
// part[bid][:] with plain coalesced stores.
__global__ __launch_bounds__(1024) void count_part(const int* __restrict__ ed3,
                                                   int* __restrict__ part) {
    __shared__ int hist[BINS];
    int bid = blockIdx.x;
    int g = bid & (NGC - 1), b = bid >> 3;
    int tid = threadIdx.x;
    for (int i = tid; i < BINS; i += 1024) hist[i] = 0;
    __syncthreads();
    int lo = g * BINS, hi = lo + BINS;
    int p0 = b * PKTB;
    int p1 = min(NE3_4, p0 + PKTB);
    const int4* ed4 = (const int4*)ed3;
    for (int idx = p0 + tid; idx < p1; idx += 1024) {
        int4 e = ed4[idx];
        int eb = idx << 2;
        int roff = ((eb >= NE) + (eb >= 2 * NE)) * N_DST;
        int i0 = roff + e.x, i1 = roff + e.y, i2 = roff + e.z, i3 = roff + e.w;
        if (i0 >= lo && i0 < hi) atomicAdd(&hist[i0 - lo], 1);
        if (i1 >= lo && i1 < hi) atomicAdd(&hist[i1 - lo], 1);
        if (i2 >= lo && i2 < hi) atomicAdd(&hist[i2 - lo], 1);
        if (i3 >= lo && i3 < hi) atomicAdd(&hist[i3 - lo], 1);
    }
    __syncthreads();
    int* pp = part + (size_t)bid * BINS;
    for (int i = tid; i < BINS; i += 1024) pp[i] = hist[i];
}

// per bin: total over 32 block partials -> cnt3; rewrite part as EXCLUSIVE
// per-block prefix (gives each place block disjoint output positions).
__global__ __launch_bounds__(256) void reduce_pfx(int* __restrict__ part,
                                                  int* __restrict__ cnt3) {
    int bin = blockIdx.x * 256 + threadIdx.x;
    if (bin >= N3) return;
    int g = bin / BINS, lb = bin - g * BINS;
    int s = 0;
    #pragma unroll 4
    for (int b = 0; b < BPG; b++) {
        size_t o = (size_t)(b * NGC + g) * BINS + lb;
        int vv = part[o];
        part[o] = s;
        s += vv;
    }
    cnt3[bin] = s;
}

__global__ void scan_blocks(int* __restrict__ rowptr, int* __restrict__ bsum) {
    __shared__ int tmp[256];
    int i = blockIdx.x * 256 + threadIdx.x;
    int x = (i < N3) ? rowptr[i] : 0;
    tmp[threadIdx.x] = x;
    __syncthreads();
    #pragma unroll
    for (int off = 1; off < 256; off <<= 1) {
        int v = (threadIdx.x >= off) ? tmp[threadIdx.x - off] : 0;
        __syncthreads();
        tmp[threadIdx.x] += v;
        __syncthreads();
    }
    if (i < N3) rowptr[i] = tmp[threadIdx.x] - x;
    if (threadIdx.x == 255) bsum[blockIdx.x] = tmp[255];
}

// each block sums bsum[0..bid) itself (L2-resident)
__global__ __launch_bounds__(256) void add_offsets2(int* __restrict__ rowptr,
                                                    const int* __restrict__ bsum) {
    __shared__ int rr[4];
    int bid = blockIdx.x, tid = threadIdx.x;
    int s = 0;
    for (int j = tid; j < bid; j += 256) s += bsum[j];
    #pragma unroll
    for (int off = 32; off; off >>= 1) s += __shfl_xor(s, off);
    if ((tid & 63) == 0) rr[tid >> 6] = s;
    __syncthreads();
    int base = rr[0] + rr[1] + rr[2] + rr[3];
    int i = bid * 256 + tid;
    if (i < N3) rowptr[i] += base;
    if (i == 0) rowptr[N3] = NE3;
}

// ---------- place via LDS cursors (ZERO device atomics) ----------
// LDS cursor[lb] = rowptr3[bin] + per-block prefix -> absolute positions.
// Same edge slicing as count_part; stores land in group g's ~1.5 MB csr
// window (XCD-L2-resident, bid&7 affinity).
__global__ __launch_bounds__(1024) void place_lds(const int* __restrict__ es3,
                                                  const int* __restrict__ ed3,
                                                  const int* __restrict__ rowptr3,
                                                  const int* __restrict__ part,
                                                  int* __restrict__ csr_src) {
    __shared__ int cur[BINS];
    int bid = blockIdx.x;
    int g = bid & (NGC - 1), b = bid >> 3;
    int tid = threadIdx.x;
    const int* pp = part + (size_t)bid * BINS;
    const int* rp = rowptr3 + g * BINS;
    for (int i = tid; i < BINS; i += 1024) cur[i] = rp[i] + pp[i];
    __syncthreads();
    int lo = g * BINS, hi = lo + BINS;
    int p0 = b * PKTB;
    int p1 = min(NE3_4, p0 + PKTB);
    const int4* ed4 = (const int4*)ed3;
    const int4* es4 = (const int4*)es3;
    for (int idx = p0 + tid; idx < p1; idx += 1024) {
        int4 e = ed4[idx];
        int eb = idx << 2;
        int roff = ((eb >= NE) + (eb >= 2 * NE)) * N_DST;
        int i0 = roff + e.x, i1 = roff + e.y, i2 = roff + e.z, i3 = roff + e.w;
        bool m0 = i0 >= lo && i0 < hi, m1 = i1 >= lo && i1 < hi;
        bool m2 = i2 >= lo && i2 < hi, m3 = i3 >= lo && i3 < hi;
        if (m0 | m1 | m2 | m3) {
            int4 s = es4[idx];
            if (m0) { int p = atomicAdd(&cur[i0 - lo], 1); csr_src[p] = s.x; }
            if (m1) { int p = atomicAdd(&cur[i1 - lo], 1); csr_src[p] = s.y; }
            if (m2) { int p = atomicAdd(&cur[i2 - lo], 1); csr_src[p] = s.z; }
            if (m3) { int p = atomicAdd(&cur[i3 - lo], 1); csr_src[p] = s.w; }
        }
    }
}

// ---------- MFMA GEMM: H = X @ W (bf16x2), fused el ----------
__global__ __launch_bounds__(256) void gemm_h_all(const float* __restrict__ src_feat,
        const unsigned short* __restrict__ Wh, const float* __restrict__ attn_l,
        unsigned short* __restrict__ H3, float* __restrict__ el3) {
    __shared__ short Xh[64 * 128], Xl[64 * 128];   // 16 KB each
    __shared__ short Bh[128 * 128];                // 32 KB
    int tid = threadIdx.x;
    int rb = blockIdx.x / NBH64, bb = blockIdx.x % NBH64;
    const float* X = src_feat + (size_t)rb * N_SRC * D;
    const unsigned short* WhR = Wh + (size_t)rb * D * D;
    const float* al = attn_l + rb * D;
    unsigned short* H = H3 + (size_t)rb * N_SRC * D;
    float* el = el3 + (size_t)rb * N_SRC;
    size_t row0 = (size_t)bb * 64;
    #pragma unroll
    for (int p = 0; p < 8; p++) {
        int c = p * 256 + tid;
        int m = c >> 5, c4 = c & 31;
        float4 xv = make_float4(0.f, 0.f, 0.f, 0.f);
        if (row0 + m < N_SRC) xv = ((const float4*)(X + (row0 + m) * D))[c4];
        unsigned h01 = cvt_pk_bf16(xv.x, xv.y);
        unsigned h23 = cvt_pk_bf16(xv.z, xv.w);
        float hx = ubits(h01 << 16), hy = ubits(h01 & 0xffff0000u);
        float hz = ubits(h23 << 16), hw = ubits(h23 & 0xffff0000u);
        unsigned l01 = cvt_pk_bf16(xv.x - hx, xv.y - hy);
        unsigned l23 = cvt_pk_bf16(xv.z - hz, xv.w - hw);
        int idx = m * 128 + (((c4 >> 1) ^ (m & 7)) << 3) + ((c4 & 1) << 2);
        *(uint2*)&Xh[idx] = make_uint2(h01, h23);
        *(uint2*)&Xl[idx] = make_uint2(l01, l23);
    }
    #pragma unroll
    for (int p = 0; p < 8; p++) {
        int c = p * 256 + tid;
        int n = c >> 4, cb = c & 15;
        int idx = n * 128 + ((cb ^ (n & 7)) << 3);
        *(uint4*)&Bh[idx] = ((const uint4*)WhR)[c];
    }
    __syncthreads();

    int w = tid >> 6, lane = tid & 63, lr = lane & 15, lg = lane >> 4;
    f32x4 acc[8];
    #pragma unroll
    for (int nt = 0; nt < 8; nt++) acc[nt] = (f32x4){0.f, 0.f, 0.f, 0.f};
    int m = w * 16 + lr;
    #pragma unroll
    for (int kk = 0; kk < 4; kk++) {
        int cb = kk * 4 + lg;
        int ia = m * 128 + ((cb ^ (m & 7)) << 3);
        bf16x8 ah = *(const bf16x8*)&Xh[ia];
        bf16x8 alo = *(const bf16x8*)&Xl[ia];
        #pragma unroll
        for (int nt = 0; nt < 8; nt++) {
            int n = nt * 16 + lr;
            int ib = n * 128 + ((cb ^ (n & 7)) << 3);
            bf16x8 bh = *(const bf16x8*)&Bh[ib];
            acc[nt] = __builtin_amdgcn_mfma_f32_16x16x32_bf16(ah, bh, acc[nt], 0, 0, 0);
            acc[nt] = __builtin_amdgcn_mfma_f32_16x16x32_bf16(alo, bh, acc[nt], 0, 0, 0);
        }
    }
    float alv[8];
    #pragma unroll
    for (int nt = 0; nt < 8; nt++) alv[nt] = al[nt * 16 + lr];
    #pragma unroll
    for (int reg = 0; reg < 4; reg++) {
        float ep = 0.f;
        #pragma unroll
        for (int nt = 0; nt < 8; nt++) ep = fmaf(acc[nt][reg], alv[nt], ep);
        ep += __shfl_xor(ep, 1); ep += __shfl_xor(ep, 2);
        ep += __shfl_xor(ep, 4); ep += __shfl_xor(ep, 8);
        size_t row = row0 + w * 16 + lg * 4 + reg;
        if (lr == 0 && row < N_SRC) el[row] = ep;
    }
    short* Ht = Xh;
    #pragma unroll
    for (int reg = 0; reg < 4; reg++) {
        int rowl = w * 16 + lg * 4 + reg;
        #pragma unroll
        for (int nt = 0; nt < 8; nt++)
            Ht[rowl * 128 + nt * 16 + lr] = (short)f2b(acc[nt][reg]);
    }
    __syncthreads();
    #pragma unroll
    for (int p = 0; p < 4; p++) {
        int c = p * 256 + tid;
        int mm = c >> 4, q = c & 15;
        size_t row = row0 + mm;
        if (row < N_SRC)
            ((uint4*)(H + row * D))[q] = *(const uint4*)&Ht[mm * 128 + q * 8];
    }
}

// ---------- MFMA GEMM: semantic partials (z is bf16) ----------
__global__ __launch_bounds__(512) void gemm_sem(const unsigned short* __restrict__ Z,
        const unsigned short* __restrict__ W1t, const float* __restrict__ b1,
        const float* __restrict__ w2, float* __restrict__ psem) {
    __shared__ short Xh[16384], Bh[16384];
    __shared__ float redw[8][4];
    int tid = threadIdx.x;
    size_t row0 = (size_t)blockIdx.x * 128;
    #pragma unroll
    for (int p = 0; p < 4; p++) {
        int c = p * 512 + tid;
        int m = c >> 4, cb = c & 15;
        uint4 xv = make_uint4(0u, 0u, 0u, 0u);
        if (row0 + m < NROWS_SEM) xv = ((const uint4*)(Z + (row0 + m) * D))[cb];
        int idx = m * 128 + ((cb ^ (m & 7)) << 3);
        *(uint4*)&Xh[idx] = xv;
    }
    #pragma unroll
    for (int p = 0; p < 4; p++) {
        int c = p * 512 + tid;
        int n = c >> 4, cb = c & 15;
        int idx = n * 128 + ((cb ^ (n & 7)) << 3);
        *(uint4*)&Bh[idx] = ((const uint4*)W1t)[c];
    }
    __syncthreads();

    int w = tid >> 6, lane = tid & 63, lr = lane & 15, lg = lane >> 4;
    f32x4 acc[8];
    #pragma unroll
    for (int nt = 0; nt < 8; nt++) acc[nt] = (f32x4){0.f, 0.f, 0.f, 0.f};
    int m = w * 16 + lr;
    #pragma unroll
    for (int kk = 0; kk < 4; kk++) {
        int cb = kk * 4 + lg;
        int ia = m * 128 + ((cb ^ (m & 7)) << 3);
        bf16x8 ah = *(const bf16x8*)&Xh[ia];
        #pragma unroll
        for (int nt = 0; nt < 8; nt++) {
            int n = nt * 16 + lr;
            int ib = n * 128 + ((cb ^ (n & 7)) << 3);
            bf16x8 bh = *(const bf16x8*)&Bh[ib];
            acc[nt] = __builtin_amdgcn_mfma_f32_16x16x32_bf16(ah, bh, acc[nt], 0, 0, 0);
        }
    }
    float b1v[8], w2v[8];
    #pragma unroll
    for (int nt = 0; nt < 8; nt++) { b1v[nt] = b1[nt * 16 + lr]; w2v[nt] = w2[nt * 16 + lr]; }
    float rs0 = 0.f, rs1 = 0.f, rs2 = 0.f;
    #pragma unroll
    for (int reg = 0; reg < 4; reg++) {
        size_t row = row0 + w * 16 + lg * 4 + reg;
        float sv = 0.f;
        #pragma unroll
        for (int nt = 0; nt < 8; nt++)
            sv += tanhf(acc[nt][reg] + b1v[nt]) * w2v[nt];
        sv += __shfl_xor(sv, 1); sv += __shfl_xor(sv, 2);
        sv += __shfl_xor(sv, 4); sv += __shfl_xor(sv, 8);
        if (lr == 0 && row < NROWS_SEM) {
            int r = (int)(row / N_DST);
            if (r == 0) rs0 += sv; else if (r == 1) rs1 += sv; else rs2 += sv;
        }
    }
    rs0 += __shfl_xor(rs0, 16); rs0 += __shfl_xor(rs0, 32);
    rs1 += __shfl_xor(rs1, 16); rs1 += __shfl_xor(rs1, 32);
    rs2 += __shfl_xor(rs2, 16); rs2 += __shfl_xor(rs2, 32);
    if (lane == 0) { redw[w][0] = rs0; redw[w][1] = rs1; redw[w][2] = rs2; }
    __syncthreads();
    if (tid < 3) {
        float s = 0.f;
        #pragma unroll
        for (int i = 0; i < 8; i++) s += redw[i][tid];
        psem[blockIdx.x * 3 + tid] = s;
    }
}

// ---------- per-(r,dst) gather + softmax + elu (round-13 verified) ----------
__global__ __launch_bounds__(256) void aggregate_all(const unsigned short* __restrict__ hsrc3,
                                                     const int* __restrict__ csr_src,
                                                     const int* __restrict__ rowptr3,
                                                     const float* __restrict__ el3,
                                                     const float* __restrict__ er3,
                                                     const float* __restrict__ gat_bias,
                                                     unsigned short* __restrict__ z3) {
    int gw3 = __builtin_amdgcn_readfirstlane((int)((blockIdx.x * blockDim.x + threadIdx.x) >> 6));
    int lane = threadIdx.x & 63;
    if (gw3 >= N3) return;
    int r = gw3 / N_DST;
    int beg = __builtin_amdgcn_readfirstlane(rowptr3[gw3]);
    int end = __builtin_amdgcn_readfirstlane(rowptr3[gw3 + 1]);
    float erd = er3[gw3];
    const char* hsb = (const char*)(hsrc3 + (size_t)r * N_SRC * D);
    const char* elb = (const char*)(el3 + (size_t)r * N_SRC);
    unsigned loff = ((unsigned)lane) << 2;
    float2 acc = make_float2(0.f, 0.f);
    float sum = 0.f;
    int i = beg;
    for (; i + 8 <= end; i += 8) {
        int s[8];
        #pragma unroll
        for (int k = 0; k < 8; k++)
            s[k] = __builtin_amdgcn_readfirstlane(csr_src[i + k]);
        float x[8];
        #pragma unroll
        for (int k = 0; k < 8; k++) {
            float e = *(const float*)(elb + ((unsigned)s[k] << 2)) + erd;
            e = fmaxf(e, NEG * e);
            x[k] = __expf(e);
        }
        ushort2 u[8];
        #pragma unroll
        for (int k = 0; k < 8; k++)
            u[k] = *(const ushort2*)(hsb + (((unsigned)s[k] << 8) + loff));
        #pragma unroll
        for (int k = 0; k < 8; k++) {
            acc.x = fmaf(x[k], b2f(u[k].x), acc.x);
            acc.y = fmaf(x[k], b2f(u[k].y), acc.y);
            sum += x[k];
        }
    }
    for (; i + 4 <= end; i += 4) {
        int s0 = __builtin_amdgcn_readfirstlane(csr_src[i]);
        int s1 = __builtin_amdgcn_readfirstlane(csr_src[i + 1]);
        int s2 = __builtin_amdgcn_readfirstlane(csr_src[i + 2]);
        int s3 = __builtin_amdgcn_readfirstlane(csr_src[i + 3]);
        float e0 = *(const float*)(elb + ((unsigned)s0 << 2)) + erd;
        float e1 = *(const float*)(elb + ((unsigned)s1 << 2)) + erd;
        float e2 = *(const float*)(elb + ((unsigned)s2 << 2)) + erd;
        float e3 = *(const float*)(elb + ((unsigned)s3 << 2)) + erd;
        e0 = fmaxf(e0, NEG * e0); e1 = fmaxf(e1, NEG * e1);
        e2 = fmaxf(e2, NEG * e2); e3 = fmaxf(e3, NEG * e3);
        float x0 = __expf(e0), x1 = __expf(e1);
        float x2 = __expf(e2), x3 = __expf(e3);
        ushort2 u0 = *(const ushort2*)(hsb + (((unsigned)s0 << 8) + loff));
        ushort2 u1 = *(const ushort2*)(hsb + (((unsigned)s1 << 8) + loff));
        ushort2 u2 = *(const ushort2*)(hsb + (((unsigned)s2 << 8) + loff));
        ushort2 u3 = *(const ushort2*)(hsb + (((unsigned)s3 << 8) + loff));
        acc.x = fmaf(x0, b2f(u0.x), acc.x);
        acc.y = fmaf(x0, b2f(u0.y), acc.y);
        acc.x = fmaf(x1, b2f(u1.x), acc.x);
        acc.y = fmaf(x1, b2f(u1.y), acc.y);
        acc.x = fmaf(x2, b2f(u2.x), acc.x);
        acc.y = fmaf(x2, b2f(u2.y), acc.y);
        acc.x = fmaf(x3, b2f(u3.x), acc.x);
        acc.y = fmaf(x3, b2f(u3.y), acc.y);
        sum += (x0 + x1) + (x2 + x3);
    }
    for (; i < end; i++) {
        int s0 = __builtin_amdgcn_readfirstlane(csr_src[i]);
        float e0 = *(const float*)(elb + ((unsigned)s0 << 2)) + erd;
        e0 = fmaxf(e0, NEG * e0);
        float x0 = __expf(e0);
        ushort2 u0 = *(const ushort2*)(hsb + (((unsigned)s0 << 8) + loff));
        acc.x = fmaf(x0, b2f(u0.x), acc.x);
        acc.y = fmaf(x0, b2f(u0.y), acc.y);
        sum += x0;
    }
    float inv = sum > 0.f ? 1.f / sum : 0.f;
    float2 b = ((const float2*)(gat_bias + r * D))[lane];
    ushort2 zu;
    zu.x = f2b(eluf(fmaf(acc.x, inv, b.x)));
    zu.y = f2b(eluf(fmaf(acc.y, inv, b.y)));
    ((ushort2*)(z3 + (size_t)gw3 * D))[lane] = zu;
}

__global__ void finalize_a(const float* __restrict__ psem, float* __restrict__ a_ws,
                           float* __restrict__ out_tail) {
    __shared__ float red[4][4];
    float s0 = 0.f, s1 = 0.f, s2 = 0.f;
    for (int b = threadIdx.x; b < NBS; b += 256) {
        s0 += psem[b * 3]; s1 += psem[b * 3 + 1]; s2 += psem[b * 3 + 2];
    }
    #pragma unroll
    for (int off = 32; off; off >>= 1) {
        s0 += __shfl_xor(s0, off); s1 += __shfl_xor(s1, off); s2 += __shfl_xor(s2, off);
    }
    int w = threadIdx.x >> 6;
    if ((threadIdx.x & 63) == 0) { red[w][0] = s0; red[w][1] = s1; red[w][2] = s2; }
    __syncthreads();
    if (threadIdx.x == 0) {
        float w0 = 0.f, w1 = 0.f, w2v = 0.f;
        #pragma unroll
        for (int i = 0; i < 4; i++) { w0 += red[i][0]; w1 += red[i][1]; w2v += red[i][2]; }
        w0 /= (float)N_DST; w1 /= (float)N_DST; w2v /= (float)N_DST;
        float m = fmaxf(w0, fmaxf(w1, w2v));
        float e0 = expf(w0 - m), e1 = expf(w1 - m), e2 = expf(w2v - m);
        float s = e0 + e1 + e2;
        a_ws[0] = e0 / s; a_ws[1] = e1 / s; a_ws[2] = e2 / s;
        out_tail[0] = e0 / s; out_tail[1] = e1 / s; out_tail[2] = e2 / s;
    }
}

// z_out = sum_r a[r] * z[r]  (z bf16, out fp32), 8 elems/thread
__global__ __launch_bounds__(256) void combine(const unsigned short* __restrict__ z3,
                                               const float* __restrict__ a,
                                               float* __restrict__ out) {
    size_t f = (size_t)blockIdx.x * blockDim.x + threadIdx.x;  // uint4 (8 bf16) index
    if (f >= (size_t)N_DST * D / 8) return;
    float accv[8] = {};
    #pragma unroll
    for (int r = 0; r < R; r++) {
        float ar = a[r];
        uint4 u = ((const uint4*)z3)[(size_t)r * (N_DST * D / 8) + f];
        unsigned int uu[4] = {u.x, u.y, u.z, u.w};
        #pragma unroll
        for (int q = 0; q < 4; q++) {
            accv[2 * q]     = fmaf(ar, b2f((unsigned short)(uu[q] & 0xffff)), accv[2 * q]);
            accv[2 * q + 1] = fmaf(ar, b2f((unsigned short)(uu[q] >> 16)), accv[2 * q + 1]);
        }
    }
    float4* o4 = (float4*)(out + f * 8);
    o4[0] = make_float4(accv[0], accv[1], accv[2], accv[3]);
    o4[1] = make_float4(accv[4], accv[5], accv[6], accv[7]);
}

extern "C" void kernel_launch(void* const* d_in, const int* in_sizes, int n_in,
                              void* d_out, int out_size, void* d_ws, size_t ws_size,
                              hipStream_t stream) {
    const float* dst_feat = (const float*)d_in[0];
    const float* src_feat = (const float*)d_in[1];
    const float* fcW      = (const float*)d_in[2];
    const float* attn_l   = (const float*)d_in[3];
    const float* attn_r   = (const float*)d_in[4];
    const float* gat_bias = (const float*)d_in[5];
    const float* sem_W1   = (const float*)d_in[6];
    const float* sem_b1   = (const float*)d_in[7];
    const float* sem_w2   = (const float*)d_in[8];
    const int* edge_src   = (const int*)d_in[9];
    const int* edge_dst   = (const int*)d_in[10];
    float* out = (float*)d_out;

    char* p = (char*)d_ws;
    auto alloc = [&](size_t bytes) {
        p = (char*)(((uintptr_t)p + 255) & ~(uintptr_t)255);
        char* r = p; p += bytes; return (void*)r;
    };
    unsigned short* z3   = (unsigned short*)alloc((size_t)N3 * D * sizeof(short));
    unsigned short* hsrc3= (unsigned short*)alloc((size_t)R * N_SRC * D * sizeof(short));
    float* el3    = (float*)alloc((size_t)R * N_SRC * sizeof(float));
    float* er3    = (float*)alloc((size_t)R * N_DST * sizeof(float));
    float* v      = (float*)alloc(R * D * sizeof(float));
    float* a      = (float*)alloc(R * sizeof(float));
    float* psem   = (float*)alloc((size_t)NBS * 3 * sizeof(float));
    unsigned short* Whi  = (unsigned short*)alloc((size_t)R * D * D * sizeof(short));
    unsigned short* W1t  = (unsigned short*)alloc((size_t)D * D * sizeof(short));
    int* rowptr3 = (int*)alloc((size_t)(N3 + 1) * sizeof(int));
    int* bsum    = (int*)alloc(2048 * sizeof(int));
    int* csr_src = (int*)alloc((size_t)NE3 * sizeof(int));
    int* part    = (int*)alloc((size_t)CBLK * BINS * sizeof(int));   // 38.4 MB

    // 1. prologue: W prep + v + W1t
    prep_all<<<R + 1, 256, 0, stream>>>(fcW, attn_r, sem_W1, Whi, W1t, v);
    // 2. per-block LDS histograms (no device atomics)
    count_part<<<CBLK, 1024, 0, stream>>>(edge_dst, part);
    // 3. er (BW-bound, independent)
    er_all<<<N_DST / 4, 256, 0, stream>>>(dst_feat, v, er3);
    // 4. reduce partials -> cnt3; part -> per-block exclusive prefix
    reduce_pfx<<<NB3, 256, 0, stream>>>(part, rowptr3);
    // 5-6. global scan of cnt3 -> rowptr3
    scan_blocks<<<NB3, 256, 0, stream>>>(rowptr3, bsum);
    add_offsets2<<<NB3, 256, 0, stream>>>(rowptr3, bsum);
    // 7. place via LDS cursors (no device atomics)
    place_lds<<<CBLK, 1024, 0, stream>>>(edge_src, edge_dst, rowptr3, part, csr_src);
    // 8. gemm_h
    gemm_h_all<<<R * NBH64, 256, 0, stream>>>(src_feat, Whi, attn_l, hsrc3, el3);
    // 9. gather + softmax + elu -> z (bf16)
    aggregate_all<<<N3 / 4, 256, 0, stream>>>(hsrc3, csr_src, rowptr3, el3, er3,
                                              gat_bias, z3);
    // 10-12. semantic attention + combine
    gemm_sem<<<NBS, 512, 0, stream>>>(z3, W1t, sem_b1, sem_w2, psem);
    finalize_a<<<1, 256, 0, stream>>>(psem, a, out + (size_t)N_DST * D);
    combine<<<(N_DST * D / 8 + 255) / 256, 256, 0, stream>>>(z3, a, out);
}